// Round 8
// baseline (621.300 us; speedup 1.0000x reference)
//
#include <hip/hip_runtime.h>

#define NN 100000      // nodes
#define EE 600000      // edges per etype
#define F  128         // IN == H == 128
#define NF (NN * F)
#define NPAD 100096    // 782 * 128 (row-padded for full 128-row tiles)
#define SLOT_CAP 32    // P(in_deg > 32 | Poisson(6)) ~ 1e-16 — safe
#define NBUCK 391      // ceil(100000/256) coarse buckets of 256 nodes
#define BSHIFT 8       // 256 nodes per bucket
#define BCAP 2048      // edge capacity per bucket (mean 1536, +13 sigma)
#define ITEMS 16       // edges per thread in bin role
#define FEATBLK 12500  // NF/4/256
#define BINBLK 147     // ceil(EE / (256*ITEMS))
#define PREPBLK 320    // 5 weights * 64 blocks
#define MMBLK 782      // NPAD/F

typedef __attribute__((ext_vector_type(8))) _Float16 half8;
typedef __attribute__((ext_vector_type(4))) float floatx4;
typedef __attribute__((ext_vector_type(4))) unsigned short ushortx4;

__device__ inline unsigned short f2h(float x) {
    union { _Float16 h; unsigned short u; } v; v.h = (_Float16)x; return v.u;
}
__device__ inline float h2f(unsigned short u) {
    union { unsigned short u; _Float16 h; } v; v.u = u; return (float)v.h;
}

__device__ inline void gld_lds16(const void* g, void* l) {
    __builtin_amdgcn_global_load_lds(
        (const __attribute__((address_space(1))) void*)g,
        (__attribute__((address_space(3))) void*)l, 16, 0, 0);
}

// ---------------- überkernel 1: featfp16 ∥ bin ∥ weight-prep ---------------
__global__ __launch_bounds__(256) void prep_bin_kernel(
        const float* __restrict__ feat, unsigned short* __restrict__ fb,
        const int* __restrict__ src0, const int* __restrict__ src1,
        const int* __restrict__ src2, const int* __restrict__ dst0,
        const int* __restrict__ dst1, const int* __restrict__ dst2,
        const float* __restrict__ W0, const float* __restrict__ W1,
        const float* __restrict__ W2, const float* __restrict__ W3,
        const float* __restrict__ W4, unsigned short* __restrict__ Wt,
        int* __restrict__ gcnt_d, int* __restrict__ gcnt_s,
        unsigned* __restrict__ bins_d, int* __restrict__ bins_s) {
    __shared__ int hist_d[NBUCK], hist_s[NBUCK];
    __shared__ int base_d[NBUCK], base_s[NBUCK];
    int bid = blockIdx.x, tid = threadIdx.x;

    if (bid < FEATBLK) {               // ---- feat fp32 -> fp16 role
        int t = bid * 256 + tid;
        float4 v = ((const float4*)feat)[t];
        ushortx4 r;
        r.x = f2h(v.x); r.y = f2h(v.y); r.z = f2h(v.z); r.w = f2h(v.w);
        ((ushortx4*)fb)[t] = r;
        return;
    }
    if (bid < FEATBLK + 3 * BINBLK) {  // ---- bin role
        int b2 = bid - FEATBLK;
        int e = b2 / BINBLK, c = b2 % BINBLK;
        const int* sp = (e == 0) ? src0 : (e == 1) ? src1 : src2;
        const int* dp = (e == 0) ? dst0 : (e == 1) ? dst1 : dst2;
        for (int k = tid; k < NBUCK; k += 256) { hist_d[k] = 0; hist_s[k] = 0; }
        __syncthreads();
        int i0 = c * (256 * ITEMS) + tid;
        int sv[ITEMS], dv[ITEMS], rkd[ITEMS], rks[ITEMS];
#pragma unroll
        for (int j = 0; j < ITEMS; ++j) {
            int i = i0 + j * 256;
            if (i < EE) {
                sv[j] = sp[i]; dv[j] = dp[i];
                rkd[j] = atomicAdd(&hist_d[dv[j] >> BSHIFT], 1);
                rks[j] = atomicAdd(&hist_s[sv[j] >> BSHIFT], 1);
            }
        }
        __syncthreads();
        for (int k = tid; k < NBUCK; k += 256) {
            base_d[k] = atomicAdd(&gcnt_d[e * NBUCK + k], hist_d[k]);
            base_s[k] = atomicAdd(&gcnt_s[e * NBUCK + k], hist_s[k]);
        }
        __syncthreads();
#pragma unroll
        for (int j = 0; j < ITEMS; ++j) {
            int i = i0 + j * 256;
            if (i < EE) {
                int bd = dv[j] >> BSHIFT, bs = sv[j] >> BSHIFT;
                int pd = base_d[bd] + rkd[j], ps = base_s[bs] + rks[j];
                if (pd < BCAP)    // packed: s in bits 31..8, d_low in bits 7..0
                    bins_d[(size_t)(e * NBUCK + bd) * BCAP + pd] =
                        ((unsigned)sv[j] << BSHIFT) | ((unsigned)dv[j] & 255u);
                if (ps < BCAP)
                    bins_s[(size_t)(e * NBUCK + bs) * BCAP + ps] = sv[j];
            }
        }
        return;
    }
    // ---- weight-prep role: Wt[n][k] = fp16(W[k][n]), 5 weights
    int p = bid - FEATBLK - 3 * BINBLK;   // 0..319
    int w = p >> 6;
    const float* W = (w == 0) ? W0 : (w == 1) ? W1 : (w == 2) ? W2 : (w == 3) ? W3 : W4;
    int t = (p & 63) * 256 + tid;         // 0..16383
    int k = t >> 7, n = t & 127;
    Wt[w * F * F + n * F + k] = f2h(W[t]);
}

// ---------------- bucket: per-bucket slot build in LDS, coalesced out ------
// Slots d-major: slots[(e*NN + d)*32 + p]. Outputs in_cnt, rs (out-deg),
// rsin (in-deg rsqrt, consumed by h_rec epilogue).
__global__ __launch_bounds__(256) void bucket_kernel(
        const int* __restrict__ gcnt_d, const int* __restrict__ gcnt_s,
        const unsigned* __restrict__ bins_d, const int* __restrict__ bins_s,
        int* __restrict__ in_cnt, float* __restrict__ rs,
        float* __restrict__ rsin, int* __restrict__ slots) {
    __shared__ int cnt[256], cnt2[256];
    __shared__ int sl[256 * SLOT_CAP];    // 32KB
    int e = blockIdx.y, b = blockIdx.x, tid = threadIdx.x;
    cnt[tid] = 0; cnt2[tid] = 0;
    __syncthreads();
    int n0 = b << BSHIFT;
    int m = gcnt_d[e * NBUCK + b]; if (m > BCAP) m = BCAP;
    const unsigned* bd = bins_d + (size_t)(e * NBUCK + b) * BCAP;
    for (int k = tid; k < m; k += 256) {
        unsigned v = bd[k];
        int ln = (int)(v & 255u);
        int p = atomicAdd(&cnt[ln], 1);
        if (p < SLOT_CAP) sl[ln * SLOT_CAP + p] = (int)(v >> BSHIFT);
    }
    int m2 = gcnt_s[e * NBUCK + b]; if (m2 > BCAP) m2 = BCAP;
    const int* bs = bins_s + (size_t)(e * NBUCK + b) * BCAP;
    for (int k = tid; k < m2; k += 256) atomicAdd(&cnt2[bs[k] - n0], 1);
    __syncthreads();
    {
        int node = n0 + tid;
        if (node < NN) {
            int ci = cnt[tid];
            in_cnt[e * NN + node] = ci;
            rsin[e * NN + node] = rsqrtf((float)(ci < 1 ? 1 : ci));
            int c = cnt2[tid];
            rs[e * NN + node] = rsqrtf((float)(c < 1 ? 1 : c));
        }
    }
    for (int k = tid; k < 256 * 8; k += 256) {     // 8 int4 per node = 32 slots
        int node = n0 + (k >> 3);
        if (node < NN) {
            int4 w = *(const int4*)&sl[(k >> 3) * SLOT_CAP + (k & 7) * 4];
            ((int4*)&slots[((size_t)e * NN + node) * SLOT_CAP])[k & 7] = w;
        }
    }
}

// ---------------- agg: per node, 3 etypes, gather FEAT rows ----------------
// agg_e[d] = Σ_s rs_out[s]·feat16[s]  (fp16 out, NT store — never re-read
// here; re-read streamed by h_rec). All 3 etypes read the SAME 25.6MB
// featbf plane (vs 77MB hpre before) -> 3x smaller random-read working set.
// Rows NN..NPAD-1 written as zeros (lim=0 path) so h_rec sees no garbage.
__global__ __launch_bounds__(256) void agg_kernel(
        const unsigned short* __restrict__ featbf,
        const int* __restrict__ slots,
        const int* __restrict__ in_cnt,
        const float* __restrict__ rs,
        unsigned short* __restrict__ agg) {
    int node = blockIdx.x * 8 + (threadIdx.x >> 5);
    int l = threadIdx.x & 31;          // col group: cols l*4..l*4+3
    if (node >= NPAD) return;

#pragma unroll
    for (int e = 0; e < 3; ++e) {
        int cnt = (node < NN) ? in_cnt[e * NN + node] : 0;
        int lim = cnt < SLOT_CAP ? cnt : SLOT_CAP;
        const int* sl = slots + ((size_t)e * NN + node) * SLOT_CAP;
        const float* rse = rs + (size_t)e * NN;
        float a0[4] = {0.f, 0.f, 0.f, 0.f}, a1[4] = {0.f, 0.f, 0.f, 0.f};
        float a2[4] = {0.f, 0.f, 0.f, 0.f}, a3[4] = {0.f, 0.f, 0.f, 0.f};
        int p = 0;
        for (; p + 4 <= lim; p += 4) {
            int4 s4 = *(const int4*)&sl[p];          // 16B aligned
            float r0 = rse[s4.x], r1 = rse[s4.y], r2 = rse[s4.z], r3 = rse[s4.w];
            ushort4 v0 = *(const ushort4*)&featbf[(size_t)s4.x * F + l * 4];
            ushort4 v1 = *(const ushort4*)&featbf[(size_t)s4.y * F + l * 4];
            ushort4 v2 = *(const ushort4*)&featbf[(size_t)s4.z * F + l * 4];
            ushort4 v3 = *(const ushort4*)&featbf[(size_t)s4.w * F + l * 4];
            a0[0] = fmaf(h2f(v0.x), r0, a0[0]); a0[1] = fmaf(h2f(v0.y), r0, a0[1]);
            a0[2] = fmaf(h2f(v0.z), r0, a0[2]); a0[3] = fmaf(h2f(v0.w), r0, a0[3]);
            a1[0] = fmaf(h2f(v1.x), r1, a1[0]); a1[1] = fmaf(h2f(v1.y), r1, a1[1]);
            a1[2] = fmaf(h2f(v1.z), r1, a1[2]); a1[3] = fmaf(h2f(v1.w), r1, a1[3]);
            a2[0] = fmaf(h2f(v2.x), r2, a2[0]); a2[1] = fmaf(h2f(v2.y), r2, a2[1]);
            a2[2] = fmaf(h2f(v2.z), r2, a2[2]); a2[3] = fmaf(h2f(v2.w), r2, a2[3]);
            a3[0] = fmaf(h2f(v3.x), r3, a3[0]); a3[1] = fmaf(h2f(v3.y), r3, a3[1]);
            a3[2] = fmaf(h2f(v3.z), r3, a3[2]); a3[3] = fmaf(h2f(v3.w), r3, a3[3]);
        }
        if (p < lim) {                               // tail: 1..3 entries
            int4 s4 = *(const int4*)&sl[p];
            int rem = lim - p;
            {
                float r0 = rse[s4.x];
                ushort4 v0 = *(const ushort4*)&featbf[(size_t)s4.x * F + l * 4];
                a0[0] = fmaf(h2f(v0.x), r0, a0[0]); a0[1] = fmaf(h2f(v0.y), r0, a0[1]);
                a0[2] = fmaf(h2f(v0.z), r0, a0[2]); a0[3] = fmaf(h2f(v0.w), r0, a0[3]);
            }
            if (rem >= 2) {
                float r1 = rse[s4.y];
                ushort4 v1 = *(const ushort4*)&featbf[(size_t)s4.y * F + l * 4];
                a1[0] = fmaf(h2f(v1.x), r1, a1[0]); a1[1] = fmaf(h2f(v1.y), r1, a1[1]);
                a1[2] = fmaf(h2f(v1.z), r1, a1[2]); a1[3] = fmaf(h2f(v1.w), r1, a1[3]);
            }
            if (rem >= 3) {
                float r2 = rse[s4.z];
                ushort4 v2 = *(const ushort4*)&featbf[(size_t)s4.z * F + l * 4];
                a2[0] = fmaf(h2f(v2.x), r2, a2[0]); a2[1] = fmaf(h2f(v2.y), r2, a2[1]);
                a2[2] = fmaf(h2f(v2.z), r2, a2[2]); a2[3] = fmaf(h2f(v2.w), r2, a2[3]);
            }
        }
        ushortx4 o;
        o.x = f2h((a0[0] + a1[0]) + (a2[0] + a3[0]));
        o.y = f2h((a0[1] + a1[1]) + (a2[1] + a3[1]));
        o.z = f2h((a0[2] + a1[2]) + (a2[2] + a3[2]));
        o.w = f2h((a0[3] + a1[3]) + (a2[3] + a3[3]));
        __builtin_nontemporal_store(
            o, (ushortx4*)&agg[((size_t)e * NPAD + node) * F + l * 4]);
    }
}

// ---------------- h_rec: h_e = relu(rs_in·(agg_e@We_e)+be), hsum tile-local,
// then rec = relu(hsum@Wr1+br1)@Wr2 + br2 — all in ONE kernel, 64KB LDS.
// hsum never touches global memory (tile rows are row-local through both
// matmuls). 5 matmuls per 128-row tile, W/A restaged through 2 LDS buffers.
__global__ __launch_bounds__(256) void h_rec_kernel(
        const unsigned short* __restrict__ agg,   // fp16 [3][NPAD][F]
        const unsigned short* __restrict__ Wt,    // fp16 [5][n][k]
        const float* __restrict__ rsin,           // [3][NN]
        const float* __restrict__ be0, const float* __restrict__ be1,
        const float* __restrict__ be2,
        const float* __restrict__ br1, const float* __restrict__ br2,
        float* __restrict__ h0, float* __restrict__ h1, float* __restrict__ h2,
        float* __restrict__ rec) {
    __shared__ unsigned short Abuf[F * F];    // 32KB: agg tiles, hsum, T
    __shared__ unsigned short Wbuf[F * F];    // 32KB: We0..2, Wr1, Wr2
    int tid = threadIdx.x;
    int lane = tid & 63, wv = tid >> 6;
    int row0 = blockIdx.x * F;

    for (int i = 0; i < 8; ++i)
        gld_lds16(Wt + i * 2048 + wv * 512 + lane * 8, Wbuf + i * 2048 + wv * 512);
    {
        const unsigned short* Asrc = agg + (size_t)row0 * F;
        for (int i = 0; i < 8; ++i)
            gld_lds16(Asrc + i * 2048 + wv * 512 + lane * 8, Abuf + i * 2048 + wv * 512);
    }
    __syncthreads();

    int wm = (wv >> 1) * 64, wn = (wv & 1) * 64;
    int q = lane >> 4, mr = lane & 15;

    float hs[4][4][4];
#pragma unroll
    for (int mi = 0; mi < 4; ++mi)
#pragma unroll
        for (int ni = 0; ni < 4; ++ni)
#pragma unroll
            for (int r = 0; r < 4; ++r) hs[mi][ni][r] = 0.f;

    floatx4 acc[4][4];
    for (int e = 0; e < 3; ++e) {
#pragma unroll
        for (int mi = 0; mi < 4; ++mi)
#pragma unroll
            for (int ni = 0; ni < 4; ++ni)
                acc[mi][ni] = (floatx4){0.f, 0.f, 0.f, 0.f};
#pragma unroll
        for (int k0 = 0; k0 < 128; k0 += 32) {
            half8 af[4], bfv[4];
#pragma unroll
            for (int t2 = 0; t2 < 4; ++t2)
                af[t2] = *(const half8*)&Abuf[(wm + t2 * 16 + mr) * F + k0 + q * 8];
#pragma unroll
            for (int t2 = 0; t2 < 4; ++t2)
                bfv[t2] = *(const half8*)&Wbuf[(wn + t2 * 16 + mr) * F + k0 + q * 8];
#pragma unroll
            for (int mi = 0; mi < 4; ++mi)
#pragma unroll
                for (int ni = 0; ni < 4; ++ni)
                    acc[mi][ni] = __builtin_amdgcn_mfma_f32_16x16x32_f16(
                        af[mi], bfv[ni], acc[mi][ni], 0, 0, 0);
        }
        __syncthreads();              // all waves done reading Abuf+Wbuf
        if (e < 2) {                  // restage next etype (overlaps epilogue)
            const unsigned short* Wn = Wt + (size_t)(e + 1) * F * F;
            for (int i = 0; i < 8; ++i)
                gld_lds16(Wn + i * 2048 + wv * 512 + lane * 8, Wbuf + i * 2048 + wv * 512);
            const unsigned short* An = agg + (size_t)(e + 1) * NPAD * F + (size_t)row0 * F;
            for (int i = 0; i < 8; ++i)
                gld_lds16(An + i * 2048 + wv * 512 + lane * 8, Abuf + i * 2048 + wv * 512);
        } else {                      // restage Wr1 (Abuf gets hsum below)
            const unsigned short* Wn = Wt + (size_t)3 * F * F;
            for (int i = 0; i < 8; ++i)
                gld_lds16(Wn + i * 2048 + wv * 512 + lane * 8, Wbuf + i * 2048 + wv * 512);
        }

        const float* be = (e == 0) ? be0 : (e == 1) ? be1 : be2;
        float* h = (e == 0) ? h0 : (e == 1) ? h1 : h2;
        const float* rse = rsin + (size_t)e * NN;
#pragma unroll
        for (int ni = 0; ni < 4; ++ni) {
            int col = wn + ni * 16 + mr;
            float bev = be[col];
#pragma unroll
            for (int mi = 0; mi < 4; ++mi)
#pragma unroll
                for (int r = 0; r < 4; ++r) {
                    int grow = row0 + wm + mi * 16 + q * 4 + r;
                    float ri = (grow < NN) ? rse[grow] : 0.f;
                    float v = fmaxf(fmaf(acc[mi][ni][r], ri, bev), 0.f);
                    if (grow < NN)
                        __builtin_nontemporal_store(v, &h[(size_t)grow * F + col]);
                    hs[mi][ni][r] += v;
                }
        }
        __syncthreads();              // restages complete; (e=2: pre-hsum-write)
    }

    // hsum tile -> Abuf (fp16); Wr1 already staged in Wbuf
#pragma unroll
    for (int ni = 0; ni < 4; ++ni) {
        int col = wn + ni * 16 + mr;
#pragma unroll
        for (int mi = 0; mi < 4; ++mi)
#pragma unroll
            for (int r = 0; r < 4; ++r) {
                int lrow = wm + mi * 16 + q * 4 + r;
                Abuf[lrow * F + col] = f2h(hs[mi][ni][r]);
            }
    }
    __syncthreads();

#pragma unroll
    for (int mi = 0; mi < 4; ++mi)
#pragma unroll
        for (int ni = 0; ni < 4; ++ni)
            acc[mi][ni] = (floatx4){0.f, 0.f, 0.f, 0.f};
#pragma unroll
    for (int k0 = 0; k0 < 128; k0 += 32) {
        half8 af[4], bfv[4];
#pragma unroll
        for (int t2 = 0; t2 < 4; ++t2)
            af[t2] = *(const half8*)&Abuf[(wm + t2 * 16 + mr) * F + k0 + q * 8];
#pragma unroll
        for (int t2 = 0; t2 < 4; ++t2)
            bfv[t2] = *(const half8*)&Wbuf[(wn + t2 * 16 + mr) * F + k0 + q * 8];
#pragma unroll
        for (int mi = 0; mi < 4; ++mi)
#pragma unroll
            for (int ni = 0; ni < 4; ++ni)
                acc[mi][ni] = __builtin_amdgcn_mfma_f32_16x16x32_f16(
                    af[mi], bfv[ni], acc[mi][ni], 0, 0, 0);
    }
    __syncthreads();
    {   // restage Wr2; overlaps T LDS-writes
        const unsigned short* Wn = Wt + (size_t)4 * F * F;
        for (int i = 0; i < 8; ++i)
            gld_lds16(Wn + i * 2048 + wv * 512 + lane * 8, Wbuf + i * 2048 + wv * 512);
    }
    // T = fp16(relu(acc + br1)) -> Abuf
#pragma unroll
    for (int ni = 0; ni < 4; ++ni) {
        int col = wn + ni * 16 + mr;
        float bv = br1[col];
#pragma unroll
        for (int mi = 0; mi < 4; ++mi)
#pragma unroll
            for (int r = 0; r < 4; ++r) {
                int lrow = wm + mi * 16 + q * 4 + r;
                Abuf[lrow * F + col] = f2h(fmaxf(acc[mi][ni][r] + bv, 0.f));
            }
    }
    __syncthreads();

#pragma unroll
    for (int mi = 0; mi < 4; ++mi)
#pragma unroll
        for (int ni = 0; ni < 4; ++ni)
            acc[mi][ni] = (floatx4){0.f, 0.f, 0.f, 0.f};
#pragma unroll
    for (int k0 = 0; k0 < 128; k0 += 32) {
        half8 af[4], bfv[4];
#pragma unroll
        for (int t2 = 0; t2 < 4; ++t2)
            af[t2] = *(const half8*)&Abuf[(wm + t2 * 16 + mr) * F + k0 + q * 8];
#pragma unroll
        for (int t2 = 0; t2 < 4; ++t2)
            bfv[t2] = *(const half8*)&Wbuf[(wn + t2 * 16 + mr) * F + k0 + q * 8];
#pragma unroll
        for (int mi = 0; mi < 4; ++mi)
#pragma unroll
            for (int ni = 0; ni < 4; ++ni)
                acc[mi][ni] = __builtin_amdgcn_mfma_f32_16x16x32_f16(
                    af[mi], bfv[ni], acc[mi][ni], 0, 0, 0);
    }
#pragma unroll
    for (int ni = 0; ni < 4; ++ni) {
        int col = wn + ni * 16 + mr;
        float bv = br2[col];
#pragma unroll
        for (int mi = 0; mi < 4; ++mi)
#pragma unroll
            for (int r = 0; r < 4; ++r) {
                int grow = row0 + wm + mi * 16 + q * 4 + r;
                if (grow < NN)
                    __builtin_nontemporal_store(acc[mi][ni][r] + bv,
                                                &rec[(size_t)grow * F + col]);
            }
    }
}

extern "C" void kernel_launch(void* const* d_in, const int* in_sizes, int n_in,
                              void* d_out, int out_size, void* d_ws, size_t ws_size,
                              hipStream_t stream) {
    const float* feat = (const float*)d_in[0];
    const int* src[3] = {(const int*)d_in[1], (const int*)d_in[3], (const int*)d_in[5]};
    const int* dst[3] = {(const int*)d_in[2], (const int*)d_in[4], (const int*)d_in[6]};
    const float* We[3] = {(const float*)d_in[7], (const float*)d_in[9], (const float*)d_in[11]};
    const float* be[3] = {(const float*)d_in[8], (const float*)d_in[10], (const float*)d_in[12]};
    const float* Wr1 = (const float*)d_in[13];
    const float* br1 = (const float*)d_in[14];
    const float* Wr2 = (const float*)d_in[15];
    const float* br2 = (const float*)d_in[16];

    float* out = (float*)d_out;
    float* rec = out;                 // [N,128] final reconstructed
    float* h[3] = {out + NF, out + 2 * NF, out + 3 * NF};

    // workspace layout (~165 MB)
    int* gcnt_d = (int*)d_ws;                                 // 3*NBUCK
    int* gcnt_s = gcnt_d + 3 * NBUCK;                         // 3*NBUCK
    int* in_cnt = gcnt_s + 3 * NBUCK;                         // 3N
    float* rs   = (float*)(in_cnt + 3 * NN);                  // 3N (out-deg)
    float* rsin = rs + 3 * NN;                                // 3N (in-deg)
    unsigned short* Wt     = (unsigned short*)(rsin + 3 * NN); // 5*128*128 fp16
    unsigned short* featbf = Wt + 5 * F * F;                  // NPAD*F fp16
    unsigned short* agg    = featbf + (size_t)NPAD * F;       // 3*NPAD*F fp16
    int* slots = (int*)(agg + (size_t)3 * NPAD * F);          // 3*N*CAP (d-major)
    unsigned* bins_d = (unsigned*)(slots + (size_t)3 * NN * SLOT_CAP); // 9.6MB
    int*      bins_s = (int*)(bins_d + (size_t)3 * NBUCK * BCAP);      // 9.6MB

    (void)hipMemsetAsync(gcnt_d, 0, (size_t)6 * NBUCK * sizeof(int), stream);

    // feat->fp16 ∥ bin ∥ weight-prep, one launch
    prep_bin_kernel<<<FEATBLK + 3 * BINBLK + PREPBLK, 256, 0, stream>>>(
        feat, featbf, src[0], src[1], src[2], dst[0], dst[1], dst[2],
        We[0], We[1], We[2], Wr1, Wr2, Wt, gcnt_d, gcnt_s, bins_d, bins_s);

    // slot lists + degrees
    bucket_kernel<<<dim3(NBUCK, 3), 256, 0, stream>>>(
        gcnt_d, gcnt_s, bins_d, bins_s, in_cnt, rs, rsin, slots);

    // agg_e = Σ rs_out·feat16 rows (random reads on ONE 25.6MB plane)
    agg_kernel<<<NPAD / 8, 256, 0, stream>>>(featbf, slots, in_cnt, rs, agg);

    // h_e = relu(rs_in·(agg_e@We_e)+be) + rec through tile-local hsum
    h_rec_kernel<<<MMBLK, 256, 0, stream>>>(
        agg, Wt, rsin, be[0], be[1], be[2], br1, br2, h[0], h[1], h[2], rec);
}

// Round 9
// 484.961 us; speedup vs baseline: 1.2811x; 1.2811x over previous
//
#include <hip/hip_runtime.h>

#define NN 100000      // nodes
#define EE 600000      // edges per etype
#define F  128         // IN == H == 128
#define NF (NN * F)
#define NPAD 100096    // 782 * 128 (row-padded for full 128-row tiles)
#define SLOT_CAP 32    // P(in_deg > 32 | Poisson(6)) ~ 1e-16 — safe
#define NBUCK 391      // ceil(100000/256) coarse buckets of 256 nodes
#define BSHIFT 8       // 256 nodes per bucket
#define BCAP 2048      // edge capacity per bucket (mean 1536, +13 sigma)
#define ITEMS 8        // edges per thread in bin role (halved: more blocks, shorter chains)
#define BINBLK 293     // ceil(EE / (256*ITEMS))
#define FEATBLK 12500  // NF/4/256
#define PREPBLK 320    // 5 weights * 64 blocks
#define MMBLK 782      // NPAD/F

typedef __attribute__((ext_vector_type(8))) short short8;
typedef __attribute__((ext_vector_type(4))) float floatx4;

__device__ inline unsigned short f2bf(float x) {
    union { float f; unsigned u; } v; v.f = x;
    unsigned r = v.u + 0x7FFF + ((v.u >> 16) & 1);   // RTN-even
    return (unsigned short)(r >> 16);
}
__device__ inline float bf2f(unsigned short b) {
    union { unsigned u; float f; } v; v.u = ((unsigned)b) << 16;
    return v.f;
}

__device__ inline void gld_lds16(const void* g, void* l) {
    __builtin_amdgcn_global_load_lds(
        (const __attribute__((address_space(1))) void*)g,
        (__attribute__((address_space(3))) void*)l, 16, 0, 0);
}

// ---------------- überkernel 1: bin ∥ weight-prep ∥ featbf -----------------
// Bin role FIRST in block order: it is the serial pole (LDS-atomic chains);
// featbf's 12500 short BW blocks previously delayed its start.
__global__ __launch_bounds__(256) void prep_bin_kernel(
        const float* __restrict__ feat, unsigned short* __restrict__ fb,
        const int* __restrict__ src0, const int* __restrict__ src1,
        const int* __restrict__ src2, const int* __restrict__ dst0,
        const int* __restrict__ dst1, const int* __restrict__ dst2,
        const float* __restrict__ W0, const float* __restrict__ W1,
        const float* __restrict__ W2, const float* __restrict__ W3,
        const float* __restrict__ W4, unsigned short* __restrict__ Wt,
        int* __restrict__ gcnt_d, int* __restrict__ gcnt_s,
        unsigned* __restrict__ bins_d, int* __restrict__ bins_s) {
    __shared__ int hist_d[NBUCK], hist_s[NBUCK];
    __shared__ int base_d[NBUCK], base_s[NBUCK];
    int bid = blockIdx.x, tid = threadIdx.x;

    if (bid < 3 * BINBLK) {            // ---- bin role (first: serial pole)
        int e = bid / BINBLK, c = bid % BINBLK;
        const int* sp = (e == 0) ? src0 : (e == 1) ? src1 : src2;
        const int* dp = (e == 0) ? dst0 : (e == 1) ? dst1 : dst2;
        for (int k = tid; k < NBUCK; k += 256) { hist_d[k] = 0; hist_s[k] = 0; }
        __syncthreads();
        int i0 = c * (256 * ITEMS) + tid;
        int sv[ITEMS], dv[ITEMS], rkd[ITEMS], rks[ITEMS];
#pragma unroll
        for (int j = 0; j < ITEMS; ++j) {
            int i = i0 + j * 256;
            if (i < EE) {
                sv[j] = sp[i]; dv[j] = dp[i];
                rkd[j] = atomicAdd(&hist_d[dv[j] >> BSHIFT], 1);
                rks[j] = atomicAdd(&hist_s[sv[j] >> BSHIFT], 1);
            }
        }
        __syncthreads();
        for (int k = tid; k < NBUCK; k += 256) {
            base_d[k] = atomicAdd(&gcnt_d[e * NBUCK + k], hist_d[k]);
            base_s[k] = atomicAdd(&gcnt_s[e * NBUCK + k], hist_s[k]);
        }
        __syncthreads();
#pragma unroll
        for (int j = 0; j < ITEMS; ++j) {
            int i = i0 + j * 256;
            if (i < EE) {
                int bd = dv[j] >> BSHIFT, bs = sv[j] >> BSHIFT;
                int pd = base_d[bd] + rkd[j], ps = base_s[bs] + rks[j];
                if (pd < BCAP)    // packed: s in bits 31..8, d_low in bits 7..0
                    bins_d[(size_t)(e * NBUCK + bd) * BCAP + pd] =
                        ((unsigned)sv[j] << BSHIFT) | ((unsigned)dv[j] & 255u);
                if (ps < BCAP)
                    bins_s[(size_t)(e * NBUCK + bs) * BCAP + ps] = sv[j];
            }
        }
        return;
    }
    if (bid < 3 * BINBLK + PREPBLK) {  // ---- weight-prep role
        int p = bid - 3 * BINBLK;      // 0..319
        int w = p >> 6;
        const float* W = (w == 0) ? W0 : (w == 1) ? W1 : (w == 2) ? W2 : (w == 3) ? W3 : W4;
        int t = (p & 63) * 256 + tid;  // 0..16383
        int k = t >> 7, n = t & 127;
        Wt[w * F * F + n * F + k] = f2bf(W[t]);
        return;
    }
    // ---- featbf role (exactly NF/4 elems)
    int t = (bid - 3 * BINBLK - PREPBLK) * 256 + tid;
    float4 v = ((const float4*)feat)[t];
    ushort4 r;
    r.x = f2bf(v.x); r.y = f2bf(v.y); r.z = f2bf(v.z); r.w = f2bf(v.w);
    ((ushort4*)fb)[t] = r;
}

// ---------------- überkernel 2: mm3 ∥ bucket, role-split -------------------
// mm3 (blocks 0..781): hpre_e = featbf @ We_e (UNSCALED — rs applied in
// gather so mm3 has no dependency on bucket output; roles co-schedule).
// bucket (blocks 782..): per-bucket slot build in LDS, coalesced out.
__global__ __launch_bounds__(256) void mm3_bucket_kernel(
        const unsigned short* __restrict__ Abf,
        const unsigned short* __restrict__ WtBase,
        unsigned short* __restrict__ hpre,
        const int* __restrict__ gcnt_d, const int* __restrict__ gcnt_s,
        const unsigned* __restrict__ bins_d, const int* __restrict__ bins_s,
        int* __restrict__ in_cnt, float* __restrict__ rs,
        int* __restrict__ slots) {
    __shared__ __align__(16) char smem[65536];
    int tid = threadIdx.x;

    if (blockIdx.x < MMBLK) {
        // ================= mm3 role =================
        unsigned short* Abuf = (unsigned short*)smem;            // 32KB
        unsigned short* Wbuf = (unsigned short*)(smem + 32768);  // 32KB
        int lane = tid & 63, wv = tid >> 6;
        int row0 = blockIdx.x * F;

        const unsigned short* Asrc = Abf + (size_t)row0 * F;
        for (int i = 0; i < 8; ++i)
            gld_lds16(Asrc + i * 2048 + wv * 512 + lane * 8, Abuf + i * 2048 + wv * 512);
        for (int i = 0; i < 8; ++i)
            gld_lds16(WtBase + i * 2048 + wv * 512 + lane * 8, Wbuf + i * 2048 + wv * 512);
        __syncthreads();

        int wm = (wv >> 1) * 64, wn = (wv & 1) * 64;
        int q = lane >> 4, mr = lane & 15;

        for (int e = 0; e < 3; ++e) {
            floatx4 acc[4][4];
#pragma unroll
            for (int mi = 0; mi < 4; ++mi)
#pragma unroll
                for (int ni = 0; ni < 4; ++ni)
                    acc[mi][ni] = (floatx4){0.f, 0.f, 0.f, 0.f};

#pragma unroll
            for (int k0 = 0; k0 < 128; k0 += 32) {
                short8 af[4], bfv[4];
#pragma unroll
                for (int t2 = 0; t2 < 4; ++t2)
                    af[t2] = *(const short8*)&Abuf[(wm + t2 * 16 + mr) * F + k0 + q * 8];
#pragma unroll
                for (int t2 = 0; t2 < 4; ++t2)
                    bfv[t2] = *(const short8*)&Wbuf[(wn + t2 * 16 + mr) * F + k0 + q * 8];
#pragma unroll
                for (int mi = 0; mi < 4; ++mi)
#pragma unroll
                    for (int ni = 0; ni < 4; ++ni)
                        acc[mi][ni] = __builtin_amdgcn_mfma_f32_16x16x32_bf16(
                            af[mi], bfv[ni], acc[mi][ni], 0, 0, 0);
            }
            __syncthreads();          // all waves done reading Wbuf
            if (e < 2) {              // restage next W; overlaps epilogue stores
                const unsigned short* Wn = WtBase + (size_t)(e + 1) * F * F;
                for (int i = 0; i < 8; ++i)
                    gld_lds16(Wn + i * 2048 + wv * 512 + lane * 8, Wbuf + i * 2048 + wv * 512);
            }

            unsigned short* Cbf = hpre + (size_t)e * NPAD * F;
#pragma unroll
            for (int ni = 0; ni < 4; ++ni) {
                int col = wn + ni * 16 + mr;
#pragma unroll
                for (int mi = 0; mi < 4; ++mi)
#pragma unroll
                    for (int r = 0; r < 4; ++r) {
                        int grow = row0 + wm + mi * 16 + q * 4 + r;
                        Cbf[(size_t)grow * F + col] = f2bf(acc[mi][ni][r]);
                    }
            }
            if (e < 2) __syncthreads();   // barrier drain completes Wbuf restage
        }
        return;
    }

    // ================= bucket role =================
    int* cnt  = (int*)smem;              // 1KB
    int* cnt2 = (int*)(smem + 1024);     // 1KB
    int* sl   = (int*)(smem + 2048);     // 32KB
    int b2 = blockIdx.x - MMBLK;
    int e = b2 / NBUCK, b = b2 % NBUCK;
    cnt[tid] = 0; cnt2[tid] = 0;
    __syncthreads();
    int n0 = b << BSHIFT;
    int m = gcnt_d[e * NBUCK + b]; if (m > BCAP) m = BCAP;
    const unsigned* bd = bins_d + (size_t)(e * NBUCK + b) * BCAP;
    for (int k = tid; k < m; k += 256) {
        unsigned v = bd[k];
        int ln = (int)(v & 255u);
        int p = atomicAdd(&cnt[ln], 1);
        if (p < SLOT_CAP) sl[ln * SLOT_CAP + p] = (int)(v >> BSHIFT);
    }
    int m2 = gcnt_s[e * NBUCK + b]; if (m2 > BCAP) m2 = BCAP;
    const int* bs = bins_s + (size_t)(e * NBUCK + b) * BCAP;
    for (int k = tid; k < m2; k += 256) atomicAdd(&cnt2[bs[k] - n0], 1);
    __syncthreads();
    {
        int node = n0 + tid;
        if (node < NN) {
            in_cnt[e * NN + node] = cnt[tid];
            int c = cnt2[tid];
            rs[e * NN + node] = rsqrtf((float)(c < 1 ? 1 : c));
        }
    }
    for (int k = tid; k < 256 * 8; k += 256) {     // 8 int4 per node = 32 slots
        int node = n0 + (k >> 3);
        if (node < NN) {
            int4 w = *(const int4*)&sl[(k >> 3) * SLOT_CAP + (k & 7) * 4];
            ((int4*)&slots[((size_t)e * NN + node) * SLOT_CAP])[k & 7] = w;
        }
    }
}

// ---------------- gather: all 3 etypes per node, rs_out fmaf per edge ------
// int4 slot loads; h outputs NONTEMPORAL (streaming, never re-read — keeps
// hpre resident in L2). L3-transaction-bound at ~4.2 TB/s effective.
__global__ __launch_bounds__(256) void gather_kernel(
        const unsigned short* __restrict__ hpre,
        const int* __restrict__ slots,
        const int* __restrict__ in_cnt,
        const float* __restrict__ rs,
        const float* __restrict__ be0, const float* __restrict__ be1,
        const float* __restrict__ be2,
        float* __restrict__ h0, float* __restrict__ h1, float* __restrict__ h2,
        unsigned short* __restrict__ hsum) {
    int node = blockIdx.x * 8 + (threadIdx.x >> 5);
    int l = threadIdx.x & 31;          // col group: cols l*4..l*4+3
    if (node >= NN) return;

    int cnt3[3];
#pragma unroll
    for (int e = 0; e < 3; ++e) cnt3[e] = in_cnt[e * NN + node];

    float hs[4] = {0.f, 0.f, 0.f, 0.f};
#pragma unroll
    for (int e = 0; e < 3; ++e) {
        int cnt = cnt3[e];
        int lim = cnt < SLOT_CAP ? cnt : SLOT_CAP;
        const int* sl = slots + ((size_t)e * NN + node) * SLOT_CAP;
        const unsigned short* hp = hpre + (size_t)e * NPAD * F;
        const float* rse = rs + (size_t)e * NN;
        float a0[4] = {0.f, 0.f, 0.f, 0.f}, a1[4] = {0.f, 0.f, 0.f, 0.f};
        float a2[4] = {0.f, 0.f, 0.f, 0.f}, a3[4] = {0.f, 0.f, 0.f, 0.f};
        int p = 0;
        for (; p + 4 <= lim; p += 4) {
            int4 s4 = *(const int4*)&sl[p];          // 16B aligned (p % 4 == 0)
            float r0 = rse[s4.x], r1 = rse[s4.y], r2 = rse[s4.z], r3 = rse[s4.w];
            ushort4 v0 = *(const ushort4*)&hp[(size_t)s4.x * F + l * 4];
            ushort4 v1 = *(const ushort4*)&hp[(size_t)s4.y * F + l * 4];
            ushort4 v2 = *(const ushort4*)&hp[(size_t)s4.z * F + l * 4];
            ushort4 v3 = *(const ushort4*)&hp[(size_t)s4.w * F + l * 4];
            a0[0] = fmaf(bf2f(v0.x), r0, a0[0]); a0[1] = fmaf(bf2f(v0.y), r0, a0[1]);
            a0[2] = fmaf(bf2f(v0.z), r0, a0[2]); a0[3] = fmaf(bf2f(v0.w), r0, a0[3]);
            a1[0] = fmaf(bf2f(v1.x), r1, a1[0]); a1[1] = fmaf(bf2f(v1.y), r1, a1[1]);
            a1[2] = fmaf(bf2f(v1.z), r1, a1[2]); a1[3] = fmaf(bf2f(v1.w), r1, a1[3]);
            a2[0] = fmaf(bf2f(v2.x), r2, a2[0]); a2[1] = fmaf(bf2f(v2.y), r2, a2[1]);
            a2[2] = fmaf(bf2f(v2.z), r2, a2[2]); a2[3] = fmaf(bf2f(v2.w), r2, a2[3]);
            a3[0] = fmaf(bf2f(v3.x), r3, a3[0]); a3[1] = fmaf(bf2f(v3.y), r3, a3[1]);
            a3[2] = fmaf(bf2f(v3.z), r3, a3[2]); a3[3] = fmaf(bf2f(v3.w), r3, a3[3]);
        }
        if (p < lim) {                               // tail: 1..3 entries, in-bounds (cap 32)
            int4 s4 = *(const int4*)&sl[p];
            int rem = lim - p;
            {
                float r0 = rse[s4.x];
                ushort4 v0 = *(const ushort4*)&hp[(size_t)s4.x * F + l * 4];
                a0[0] = fmaf(bf2f(v0.x), r0, a0[0]); a0[1] = fmaf(bf2f(v0.y), r0, a0[1]);
                a0[2] = fmaf(bf2f(v0.z), r0, a0[2]); a0[3] = fmaf(bf2f(v0.w), r0, a0[3]);
            }
            if (rem >= 2) {
                float r1 = rse[s4.y];
                ushort4 v1 = *(const ushort4*)&hp[(size_t)s4.y * F + l * 4];
                a1[0] = fmaf(bf2f(v1.x), r1, a1[0]); a1[1] = fmaf(bf2f(v1.y), r1, a1[1]);
                a1[2] = fmaf(bf2f(v1.z), r1, a1[2]); a1[3] = fmaf(bf2f(v1.w), r1, a1[3]);
            }
            if (rem >= 3) {
                float r2 = rse[s4.z];
                ushort4 v2 = *(const ushort4*)&hp[(size_t)s4.z * F + l * 4];
                a2[0] = fmaf(bf2f(v2.x), r2, a2[0]); a2[1] = fmaf(bf2f(v2.y), r2, a2[1]);
                a2[2] = fmaf(bf2f(v2.z), r2, a2[2]); a2[3] = fmaf(bf2f(v2.w), r2, a2[3]);
            }
        }
        float rin = rsqrtf((float)(cnt < 1 ? 1 : cnt));
        const float* be = (e == 0) ? be0 : (e == 1) ? be1 : be2;
        float4 bv = *(const float4*)&be[l * 4];
        floatx4 hv;
        hv.x = fmaxf(fmaf((a0[0] + a1[0]) + (a2[0] + a3[0]), rin, bv.x), 0.f);
        hv.y = fmaxf(fmaf((a0[1] + a1[1]) + (a2[1] + a3[1]), rin, bv.y), 0.f);
        hv.z = fmaxf(fmaf((a0[2] + a1[2]) + (a2[2] + a3[2]), rin, bv.z), 0.f);
        hv.w = fmaxf(fmaf((a0[3] + a1[3]) + (a2[3] + a3[3]), rin, bv.w), 0.f);
        float* h = (e == 0) ? h0 : (e == 1) ? h1 : h2;
        __builtin_nontemporal_store(hv, (floatx4*)&h[(size_t)node * F + l * 4]);
        hs[0] += hv.x; hs[1] += hv.y; hs[2] += hv.z; hs[3] += hv.w;
    }
    ushort4 o;
    o.x = f2bf(hs[0]); o.y = f2bf(hs[1]); o.z = f2bf(hs[2]); o.w = f2bf(hs[3]);
    *(ushort4*)&hsum[(size_t)node * F + l * 4] = o;   // re-read by rec: keep cached
}

// ---------------- fused rec: rec = relu(hsum@Wr1+br1)@Wr2 + br2 ------------
// 64KB LDS (2 blocks/CU): Wr2 reloaded into the single Wbuf after matmul 1.
__global__ __launch_bounds__(256) void rec_fused_kernel(
        const unsigned short* __restrict__ Abf,
        const unsigned short* __restrict__ W1t,   // [n][k] bf16
        const unsigned short* __restrict__ W2t,   // [n][k] bf16
        const float* __restrict__ br1, const float* __restrict__ br2,
        float* __restrict__ rec) {
    __shared__ unsigned short Abuf[F * F];    // 32KB: hsum tile, then T tile
    __shared__ unsigned short Wbuf[F * F];    // 32KB: Wr1, then Wr2
    int tid = threadIdx.x;
    int lane = tid & 63, wv = tid >> 6;
    int row0 = blockIdx.x * F;

    for (int i = 0; i < 8; ++i)
        gld_lds16(W1t + i * 2048 + wv * 512 + lane * 8, Wbuf + i * 2048 + wv * 512);
    const unsigned short* Asrc = Abf + (size_t)row0 * F;
    for (int i = 0; i < 8; ++i)
        gld_lds16(Asrc + i * 2048 + wv * 512 + lane * 8, Abuf + i * 2048 + wv * 512);
    __syncthreads();

    int wm = (wv >> 1) * 64, wn = (wv & 1) * 64;
    int q = lane >> 4, mr = lane & 15;

    floatx4 acc[4][4];
#pragma unroll
    for (int mi = 0; mi < 4; ++mi)
#pragma unroll
        for (int ni = 0; ni < 4; ++ni)
            acc[mi][ni] = (floatx4){0.f, 0.f, 0.f, 0.f};

#pragma unroll
    for (int k0 = 0; k0 < 128; k0 += 32) {
        short8 af[4], bfv[4];
#pragma unroll
        for (int t = 0; t < 4; ++t)
            af[t] = *(const short8*)&Abuf[(wm + t * 16 + mr) * F + k0 + q * 8];
#pragma unroll
        for (int t = 0; t < 4; ++t)
            bfv[t] = *(const short8*)&Wbuf[(wn + t * 16 + mr) * F + k0 + q * 8];
#pragma unroll
        for (int mi = 0; mi < 4; ++mi)
#pragma unroll
            for (int ni = 0; ni < 4; ++ni)
                acc[mi][ni] = __builtin_amdgcn_mfma_f32_16x16x32_bf16(
                    af[mi], bfv[ni], acc[mi][ni], 0, 0, 0);
    }

    __syncthreads();     // all waves done reading Abuf (hsum) + Wbuf (Wr1)
    for (int i = 0; i < 8; ++i)   // restage Wr2; overlaps T LDS-writes below
        gld_lds16(W2t + i * 2048 + wv * 512 + lane * 8, Wbuf + i * 2048 + wv * 512);
    // T = bf16(relu(acc + br1)) -> Abuf
#pragma unroll
    for (int ni = 0; ni < 4; ++ni) {
        int col = wn + ni * 16 + mr;
        float bv = br1[col];
#pragma unroll
        for (int mi = 0; mi < 4; ++mi)
#pragma unroll
            for (int r = 0; r < 4; ++r) {
                int lrow = wm + mi * 16 + q * 4 + r;
                Abuf[lrow * F + col] = f2bf(fmaxf(acc[mi][ni][r] + bv, 0.f));
            }
    }
    __syncthreads();     // drains ds_writes AND the Wr2 gld_lds

#pragma unroll
    for (int mi = 0; mi < 4; ++mi)
#pragma unroll
        for (int ni = 0; ni < 4; ++ni)
            acc[mi][ni] = (floatx4){0.f, 0.f, 0.f, 0.f};

#pragma unroll
    for (int k0 = 0; k0 < 128; k0 += 32) {
        short8 af[4], bfv[4];
#pragma unroll
        for (int t = 0; t < 4; ++t)
            af[t] = *(const short8*)&Abuf[(wm + t * 16 + mr) * F + k0 + q * 8];
#pragma unroll
        for (int t = 0; t < 4; ++t)
            bfv[t] = *(const short8*)&Wbuf[(wn + t * 16 + mr) * F + k0 + q * 8];
#pragma unroll
        for (int mi = 0; mi < 4; ++mi)
#pragma unroll
            for (int ni = 0; ni < 4; ++ni)
                acc[mi][ni] = __builtin_amdgcn_mfma_f32_16x16x32_bf16(
                    af[mi], bfv[ni], acc[mi][ni], 0, 0, 0);
    }

#pragma unroll
    for (int ni = 0; ni < 4; ++ni) {
        int col = wn + ni * 16 + mr;
        float bv = br2[col];
#pragma unroll
        for (int mi = 0; mi < 4; ++mi)
#pragma unroll
            for (int r = 0; r < 4; ++r) {
                int grow = row0 + wm + mi * 16 + q * 4 + r;
                if (grow < NN)
                    __builtin_nontemporal_store(acc[mi][ni][r] + bv,
                                                &rec[(size_t)grow * F + col]);
            }
    }
}

extern "C" void kernel_launch(void* const* d_in, const int* in_sizes, int n_in,
                              void* d_out, int out_size, void* d_ws, size_t ws_size,
                              hipStream_t stream) {
    const float* feat = (const float*)d_in[0];
    const int* src[3] = {(const int*)d_in[1], (const int*)d_in[3], (const int*)d_in[5]};
    const int* dst[3] = {(const int*)d_in[2], (const int*)d_in[4], (const int*)d_in[6]};
    const float* We[3] = {(const float*)d_in[7], (const float*)d_in[9], (const float*)d_in[11]};
    const float* be[3] = {(const float*)d_in[8], (const float*)d_in[10], (const float*)d_in[12]};
    const float* Wr1 = (const float*)d_in[13];
    const float* br1 = (const float*)d_in[14];
    const float* Wr2 = (const float*)d_in[15];
    const float* br2 = (const float*)d_in[16];

    float* out = (float*)d_out;
    float* rec = out;                 // [N,128] final reconstructed
    float* h[3] = {out + NF, out + 2 * NF, out + 3 * NF};

    // workspace layout (~180 MB; bins do NOT overlay hpre — mm3 writes hpre
    // concurrently with bucket reading bins)
    int* gcnt_d = (int*)d_ws;                                // 3*NBUCK
    int* gcnt_s = gcnt_d + 3 * NBUCK;                        // 3*NBUCK
    int* in_cnt = gcnt_s + 3 * NBUCK;                        // 3N
    float* rs   = (float*)(in_cnt + 3 * NN);                 // 3N
    unsigned short* Wt     = (unsigned short*)(rs + 3 * NN); // 5*128*128
    unsigned short* featbf = Wt + 5 * F * F;                 // NPAD*F
    unsigned short* hsumbf = featbf + (size_t)NPAD * F;      // NPAD*F
    unsigned short* hpre   = hsumbf + (size_t)NPAD * F;      // 3*NPAD*F
    int* slots = (int*)(hpre + (size_t)3 * NPAD * F);        // 3*N*CAP (d-major)
    unsigned* bins_d = (unsigned*)(slots + (size_t)3 * NN * SLOT_CAP); // 9.6MB
    int*      bins_s = (int*)(bins_d + (size_t)3 * NBUCK * BCAP);      // 9.6MB

    (void)hipMemsetAsync(gcnt_d, 0, (size_t)6 * NBUCK * sizeof(int), stream);

    // bin ∥ weight-prep ∥ featbf, one launch (bin first: serial pole)
    prep_bin_kernel<<<3 * BINBLK + PREPBLK + FEATBLK, 256, 0, stream>>>(
        feat, featbf, src[0], src[1], src[2], dst[0], dst[1], dst[2],
        We[0], We[1], We[2], Wr1, Wr2, Wt, gcnt_d, gcnt_s, bins_d, bins_s);

    // mm3 ∥ bucket, one launch (mm3 blocks first — long poles)
    mm3_bucket_kernel<<<MMBLK + 3 * NBUCK, 256, 0, stream>>>(
        featbf, Wt, hpre, gcnt_d, gcnt_s, bins_d, bins_s, in_cnt, rs, slots);

    // gather + rs_out·row + norm + bias + relu -> h0,h1,h2 + hsum (bf16)
    gather_kernel<<<(NN + 7) / 8, 256, 0, stream>>>(
        hpre, slots, in_cnt, rs, be[0], be[1], be[2], h[0], h[1], h[2], hsumbf);

    // rec = relu(hsum@Wr1+br1)@Wr2 + br2, T in LDS, 64KB/block
    rec_fused_kernel<<<NPAD / F, 256, 0, stream>>>(
        hsumbf, Wt + 3 * F * F, Wt + 4 * F * F, br1, br2, rec);
}